// Round 9
// baseline (157.175 us; speedup 1.0000x reference)
//
#include <hip/hip_runtime.h>
#include <hip/hip_bf16.h>

typedef __attribute__((ext_vector_type(4))) float f32x4;
typedef __attribute__((ext_vector_type(8))) short bf16x8;
typedef __attribute__((ext_vector_type(4))) unsigned int uint4v;

#define MFMA16(a, b, c) __builtin_amdgcn_mfma_f32_16x16x32_bf16(a, b, c, 0, 0, 0)

__device__ __forceinline__ unsigned short f2bf(float f) {
  union { float f; unsigned u; } v; v.f = f;
  unsigned r = v.u + 0x7fffu + ((v.u >> 16) & 1u);
  return (unsigned short)(r >> 16);
}

// y = x @ W^T + b, optional scale, M=65536 rows, N=K=128.
// OUT_MODE: 0 = bf16 row-major [M][128]
//           1 = bf16 transposed per-batch [B][128][2048]  (for V)
//           2 = f32 row-major (final output)
template<bool IN_F32, int OUT_MODE>
__global__ __launch_bounds__(256)
void proj_kernel(const void* __restrict__ xin, const float* __restrict__ W,
                 const float* __restrict__ bias, void* __restrict__ yout,
                 float scale)
{
  __shared__ __align__(16) unsigned short Ws[128][136];
  __shared__ __align__(16) unsigned short Xs[64][136];
  const int t = threadIdx.x;
  const int wid = t >> 6;
  const int lane = t & 63;
  const int ln = lane & 15, g = lane >> 4;
  const long row0 = (long)blockIdx.x * 64;

  float bz[8];
#pragma unroll
  for (int tt = 0; tt < 8; ++tt) bz[tt] = bias[tt * 16 + ln];

  // stage W [128][128] f32 -> bf16 LDS (row j, col d)
#pragma unroll
  for (int i = 0; i < 16; ++i) {
    int idx = (i * 256 + t) * 4;
    int r = idx >> 7, c = idx & 127;
    const float4 w4 = *reinterpret_cast<const float4*>(W + idx);
    ushort4 wb;
    wb.x = f2bf(w4.x); wb.y = f2bf(w4.y); wb.z = f2bf(w4.z); wb.w = f2bf(w4.w);
    *reinterpret_cast<ushort4*>(&Ws[r][c]) = wb;
  }
  // stage X tile (64 rows)
  if (IN_F32) {
    const float* x = (const float*)xin;
#pragma unroll
    for (int i = 0; i < 8; ++i) {
      int idx = (i * 256 + t) * 4;
      int r = idx >> 7, c = idx & 127;
      const float4 x4 = *reinterpret_cast<const float4*>(x + row0 * 128 + idx);
      ushort4 xb;
      xb.x = f2bf(x4.x); xb.y = f2bf(x4.y); xb.z = f2bf(x4.z); xb.w = f2bf(x4.w);
      *reinterpret_cast<ushort4*>(&Xs[r][c]) = xb;
    }
  } else {
    const unsigned short* x = (const unsigned short*)xin;
#pragma unroll
    for (int i = 0; i < 4; ++i) {
      int idx = (i * 256 + t) * 8;
      int r = idx >> 7, c = idx & 127;
      *reinterpret_cast<uint4v*>(&Xs[r][c]) =
          *reinterpret_cast<const uint4v*>(x + row0 * 128 + idx);
    }
  }
  __syncthreads();

  f32x4 acc[8];
#pragma unroll
  for (int tt = 0; tt < 8; ++tt) acc[tt] = (f32x4){0.f, 0.f, 0.f, 0.f};

#pragma unroll
  for (int c = 0; c < 4; ++c) {
    bf16x8 af = *reinterpret_cast<const bf16x8*>(&Xs[wid * 16 + ln][c * 32 + g * 8]);
#pragma unroll
    for (int tt = 0; tt < 8; ++tt) {
      bf16x8 bfr = *reinterpret_cast<const bf16x8*>(&Ws[tt * 16 + ln][c * 32 + g * 8]);
      acc[tt] = MFMA16(af, bfr, acc[tt]);
    }
  }

#pragma unroll
  for (int tt = 0; tt < 8; ++tt) {
#pragma unroll
    for (int r = 0; r < 4; ++r) {
      long row = row0 + wid * 16 + g * 4 + r;
      int col = tt * 16 + ln;
      float val = (acc[tt][r] + bz[tt]) * scale;
      if (OUT_MODE == 2) {
        ((float*)yout)[row * 128 + col] = val;
      } else if (OUT_MODE == 0) {
        ((unsigned short*)yout)[row * 128 + col] = f2bf(val);
      } else {
        long bb = row >> 11, rr = row & 2047;
        ((unsigned short*)yout)[(bb * 128 + col) * 2048 + rr] = f2bf(val);
      }
    }
  }
}

// Flash attention: Q pre-scaled by log2(e)/sqrt(128); softmax in base 2.
// 8 waves x 16 q-rows (512 threads). Single LDS buffer, round-8 proven barrier
// structure + T14 async-STAGE split. Defer-max rescale (THR=8, log2 domain).
// Qg,Kg: [B][2048][128] bf16; Vtg: [B][128][2048] bf16 (transposed); Fg: [B][2048][128] bf16
__global__ __launch_bounds__(512)
void attn_kernel(const unsigned short* __restrict__ Qg,
                 const unsigned short* __restrict__ Kg,
                 const unsigned short* __restrict__ Vtg,
                 unsigned short* __restrict__ Fg)
{
  __shared__ __align__(16) unsigned short Ks[32][136];
  __shared__ __align__(16) unsigned short Vs[128][40];
  __shared__ __align__(16) unsigned short Ps[8][16][40];

  const int t = threadIdx.x;          // 0..511
  const int wid = t >> 6;             // 0..7
  const int lane = t & 63;
  const int ln = lane & 15, g = lane >> 4;
  const int b = blockIdx.y;
  const int q0 = blockIdx.x * 128 + wid * 16;

  const unsigned short* Qb = Qg + (long)b * 2048 * 128;
  const unsigned short* Kb = Kg + (long)b * 2048 * 128;
  const unsigned short* Vb = Vtg + (long)b * 128 * 2048;

  // staging: exactly one b128 per thread for each of K and V
  const int kr = t >> 4, kc = (t & 15) * 8;   // K tile [32][128]
  const int vc = t >> 2, ko = (t & 3) * 8;    // V^T tile [128][32]

  // Q fragments in registers: 1 q-subtile x 4 d-chunks
  bf16x8 qf[4];
#pragma unroll
  for (int c = 0; c < 4; ++c)
    qf[c] = *reinterpret_cast<const bf16x8*>(
        Qb + (long)(q0 + ln) * 128 + c * 32 + g * 8);

  f32x4 o[8];
#pragma unroll
  for (int tt = 0; tt < 8; ++tt) o[tt] = (f32x4){0.f, 0.f, 0.f, 0.f};
  float mrun = -1e30f;
  float lrun = 0.f;

  // prologue: issue tile 0's loads
  uint4v kreg = *reinterpret_cast<const uint4v*>(Kb + (long)kr * 128 + kc);
  uint4v vreg = *reinterpret_cast<const uint4v*>(Vb + (long)vc * 2048 + ko);

  for (int kt = 0; kt < 64; ++kt) {
    __syncthreads();   // all waves done reading LDS from iteration kt-1
    *reinterpret_cast<uint4v*>(&Ks[kr][kc]) = kreg;
    *reinterpret_cast<uint4v*>(&Vs[vc][ko]) = vreg;
    __syncthreads();   // tile kt visible to all waves

    // issue tile kt+1's loads NOW — latency hides under this tile's compute
    if (kt < 63) {
      const int nv0 = (kt + 1) * 32;
      kreg = *reinterpret_cast<const uint4v*>(Kb + (long)(nv0 + kr) * 128 + kc);
      vreg = *reinterpret_cast<const uint4v*>(Vb + (long)vc * 2048 + nv0 + ko);
    }

    // S^T = K . Q^T : st[ts][r] = S'[q0+ln][ts*16+g*4+r]
    f32x4 st[2];
    st[0] = (f32x4){0.f, 0.f, 0.f, 0.f};
    st[1] = (f32x4){0.f, 0.f, 0.f, 0.f};
#pragma unroll
    for (int ts = 0; ts < 2; ++ts) {
#pragma unroll
      for (int c = 0; c < 4; ++c) {
        bf16x8 kf = *reinterpret_cast<const bf16x8*>(&Ks[ts * 16 + ln][c * 32 + g * 8]);
        st[ts] = MFMA16(kf, qf[c], st[ts]);
      }
    }

    // tile max per q-row: 8 in-lane + across the 4 lane-groups
    float tm = st[0][0];
#pragma unroll
    for (int ts = 0; ts < 2; ++ts)
#pragma unroll
      for (int r = 0; r < 4; ++r) tm = fmaxf(tm, st[ts][r]);
    tm = fmaxf(tm, __shfl_xor(tm, 16));
    tm = fmaxf(tm, __shfl_xor(tm, 32));

    // defer-max: only rescale when tile max meaningfully exceeds running max
    float mcur = mrun;
    if (!__all(tm <= mcur + 8.0f)) {
      float mnew = fmaxf(mcur, tm);
      float al = __builtin_amdgcn_exp2f(mcur - mnew);
      mrun = mnew;
      mcur = mnew;
      lrun *= al;
#pragma unroll
      for (int r = 0; r < 4; ++r) {
        float ar = __shfl(al, g * 4 + r);
#pragma unroll
        for (int tt = 0; tt < 8; ++tt) o[tt][r] *= ar;
      }
    }

    float p[8];
    float rs = 0.f;
#pragma unroll
    for (int ts = 0; ts < 2; ++ts)
#pragma unroll
      for (int r = 0; r < 4; ++r) {
        float pv = __builtin_amdgcn_exp2f(st[ts][r] - mcur);
        p[ts * 4 + r] = pv;
        rs += pv;
      }
    rs += __shfl_xor(rs, 16);
    rs += __shfl_xor(rs, 32);
    lrun += rs;

    // write P tile to wave-private LDS: row=q(ln), col=kv local
#pragma unroll
    for (int ts = 0; ts < 2; ++ts)
#pragma unroll
      for (int rp = 0; rp < 2; ++rp) {
        unsigned pk = (unsigned)f2bf(p[ts * 4 + rp * 2]) |
                      ((unsigned)f2bf(p[ts * 4 + rp * 2 + 1]) << 16);
        *reinterpret_cast<unsigned*>(&Ps[wid][ln][ts * 16 + g * 4 + rp * 2]) = pk;
      }
    bf16x8 pfrag = *reinterpret_cast<const bf16x8*>(&Ps[wid][ln][g * 8]);

    // PV: O += P[16x32] . V[32x128]
#pragma unroll
    for (int tt = 0; tt < 8; ++tt) {
      bf16x8 vf = *reinterpret_cast<const bf16x8*>(&Vs[tt * 16 + ln][g * 8]);
      o[tt] = MFMA16(pfrag, vf, o[tt]);
    }
  }

  // epilogue: divide by row sum, store bf16 fusion
#pragma unroll
  for (int r = 0; r < 4; ++r) {
    float lr = __shfl(lrun, g * 4 + r);
    float inv = 1.f / lr;
    long qrow = (long)b * 2048 + q0 + g * 4 + r;
#pragma unroll
    for (int tt = 0; tt < 8; ++tt)
      Fg[qrow * 128 + tt * 16 + ln] = f2bf(o[tt][r] * inv);
  }
}

extern "C" void kernel_launch(void* const* d_in, const int* in_sizes, int n_in,
                              void* d_out, int out_size, void* d_ws, size_t ws_size,
                              hipStream_t stream)
{
  (void)in_sizes; (void)n_in; (void)out_size; (void)ws_size;
  const float* smiles = (const float*)d_in[0];
  const float* image  = (const float*)d_in[1];
  const float* Wv = (const float*)d_in[2]; const float* bv = (const float*)d_in[3];
  const float* Wk = (const float*)d_in[4]; const float* bk = (const float*)d_in[5];
  const float* Wq = (const float*)d_in[6]; const float* bq = (const float*)d_in[7];
  const float* Wd = (const float*)d_in[8]; const float* bd = (const float*)d_in[9];

  unsigned short* Qw = (unsigned short*)d_ws;          // [32][2048][128] bf16
  unsigned short* Kw = Qw + 8388608;                   // [32][2048][128] bf16
  unsigned short* Vw = Kw + 8388608;                   // [32][128][2048] bf16 (V^T)
  unsigned short* Fw = Vw + 8388608;                   // [32][2048][128] bf16 fusion

  // fold 1/sqrt(128) and log2(e) into Q so softmax uses exp2
  const float qscale = 1.4426950408889634f * 0.08838834764831845f;

  dim3 blk(256);
  proj_kernel<true, 0><<<dim3(1024), blk, 0, stream>>>(image,  Wq, bq, Qw, qscale);
  proj_kernel<true, 0><<<dim3(1024), blk, 0, stream>>>(smiles, Wk, bk, Kw, 1.f);
  proj_kernel<true, 1><<<dim3(1024), blk, 0, stream>>>(smiles, Wv, bv, Vw, 1.f);
  attn_kernel<<<dim3(16, 32), dim3(512), 0, stream>>>(Qw, Kw, Vw, Fw);
  proj_kernel<false, 2><<<dim3(1024), blk, 0, stream>>>(Fw, Wd, bd, (float*)d_out, 1.f);
}

// Round 10
// 153.706 us; speedup vs baseline: 1.0226x; 1.0226x over previous
//
#include <hip/hip_runtime.h>
#include <hip/hip_bf16.h>

typedef __attribute__((ext_vector_type(4))) float f32x4;
typedef __attribute__((ext_vector_type(16))) float f32x16;
typedef __attribute__((ext_vector_type(8))) short bf16x8;
typedef __attribute__((ext_vector_type(4))) unsigned int uint4v;

#define MFMA16(a, b, c) __builtin_amdgcn_mfma_f32_16x16x32_bf16(a, b, c, 0, 0, 0)
#define MFMA32(a, b, c) __builtin_amdgcn_mfma_f32_32x32x16_bf16(a, b, c, 0, 0, 0)

__device__ __forceinline__ unsigned short f2bf(float f) {
  union { float f; unsigned u; } v; v.f = f;
  unsigned r = v.u + 0x7fffu + ((v.u >> 16) & 1u);
  return (unsigned short)(r >> 16);
}
__device__ __forceinline__ unsigned pack2(float a, float b) {
  return (unsigned)f2bf(a) | ((unsigned)f2bf(b) << 16);
}

// y = x @ W^T + b, optional scale, M=65536 rows, N=K=128.
template<bool IN_F32, int OUT_MODE>
__global__ __launch_bounds__(256)
void proj_kernel(const void* __restrict__ xin, const float* __restrict__ W,
                 const float* __restrict__ bias, void* __restrict__ yout,
                 float scale)
{
  __shared__ __align__(16) unsigned short Ws[128][136];
  __shared__ __align__(16) unsigned short Xs[64][136];
  const int t = threadIdx.x;
  const int wid = t >> 6;
  const int lane = t & 63;
  const int ln = lane & 15, g = lane >> 4;
  const long row0 = (long)blockIdx.x * 64;

  float bz[8];
#pragma unroll
  for (int tt = 0; tt < 8; ++tt) bz[tt] = bias[tt * 16 + ln];

#pragma unroll
  for (int i = 0; i < 16; ++i) {
    int idx = (i * 256 + t) * 4;
    int r = idx >> 7, c = idx & 127;
    const float4 w4 = *reinterpret_cast<const float4*>(W + idx);
    ushort4 wb;
    wb.x = f2bf(w4.x); wb.y = f2bf(w4.y); wb.z = f2bf(w4.z); wb.w = f2bf(w4.w);
    *reinterpret_cast<ushort4*>(&Ws[r][c]) = wb;
  }
  if (IN_F32) {
    const float* x = (const float*)xin;
#pragma unroll
    for (int i = 0; i < 8; ++i) {
      int idx = (i * 256 + t) * 4;
      int r = idx >> 7, c = idx & 127;
      const float4 x4 = *reinterpret_cast<const float4*>(x + row0 * 128 + idx);
      ushort4 xb;
      xb.x = f2bf(x4.x); xb.y = f2bf(x4.y); xb.z = f2bf(x4.z); xb.w = f2bf(x4.w);
      *reinterpret_cast<ushort4*>(&Xs[r][c]) = xb;
    }
  } else {
    const unsigned short* x = (const unsigned short*)xin;
#pragma unroll
    for (int i = 0; i < 4; ++i) {
      int idx = (i * 256 + t) * 8;
      int r = idx >> 7, c = idx & 127;
      *reinterpret_cast<uint4v*>(&Xs[r][c]) =
          *reinterpret_cast<const uint4v*>(x + row0 * 128 + idx);
    }
  }
  __syncthreads();

  f32x4 acc[8];
#pragma unroll
  for (int tt = 0; tt < 8; ++tt) acc[tt] = (f32x4){0.f, 0.f, 0.f, 0.f};

#pragma unroll
  for (int c = 0; c < 4; ++c) {
    bf16x8 af = *reinterpret_cast<const bf16x8*>(&Xs[wid * 16 + ln][c * 32 + g * 8]);
#pragma unroll
    for (int tt = 0; tt < 8; ++tt) {
      bf16x8 bfr = *reinterpret_cast<const bf16x8*>(&Ws[tt * 16 + ln][c * 32 + g * 8]);
      acc[tt] = MFMA16(af, bfr, acc[tt]);
    }
  }

#pragma unroll
  for (int tt = 0; tt < 8; ++tt) {
#pragma unroll
    for (int r = 0; r < 4; ++r) {
      long row = row0 + wid * 16 + g * 4 + r;
      int col = tt * 16 + ln;
      float val = (acc[tt][r] + bz[tt]) * scale;
      if (OUT_MODE == 2) {
        ((float*)yout)[row * 128 + col] = val;
      } else if (OUT_MODE == 0) {
        ((unsigned short*)yout)[row * 128 + col] = f2bf(val);
      } else {
        long bb = row >> 11, rr = row & 2047;
        ((unsigned short*)yout)[(bb * 128 + col) * 2048 + rr] = f2bf(val);
      }
    }
  }
}

// Flash attention, 32x32x16 MFMA structure. Q pre-scaled by log2(e)/sqrt(128).
// 4 waves x 32 q-rows (256 threads). Swapped QK^T (mfma(K,Q) -> S^T), softmax
// nearly lane-local (1 cross-hi shfl), in-register P exchange (no P LDS).
// Single LDS buffer + T14 async-STAGE split (round-8 proven). Defer-max THR=8.
// Qg,Kg: [B][2048][128] bf16; Vtg: [B][128][2048] bf16 (V^T); Fg: [B][2048][128] bf16
__global__ __launch_bounds__(256)
void attn_kernel(const unsigned short* __restrict__ Qg,
                 const unsigned short* __restrict__ Kg,
                 const unsigned short* __restrict__ Vtg,
                 unsigned short* __restrict__ Fg)
{
  __shared__ __align__(16) unsigned short Ks[32][136];
  __shared__ __align__(16) unsigned short Vs[128][40];

  const int t = threadIdx.x;          // 0..255
  const int lane = t & 63;
  const int q = lane & 31;            // q-row within wave tile
  const int hi = lane >> 5;           // 0/1
  const int wid = t >> 6;             // 0..3
  const int b = blockIdx.y;
  const int q0 = blockIdx.x * 128 + wid * 32;

  const unsigned short* Qb = Qg + (long)b * 2048 * 128;
  const unsigned short* Kb = Kg + (long)b * 2048 * 128;
  const unsigned short* Vb = Vtg + (long)b * 128 * 2048;

  // staging coords (2 b128 per thread each for K and V)
  const int kr = t >> 4, kc = (t & 15) * 8;   // K tile [32][128]: rows kr, kr+16
  const int vc = t >> 2, ko = (t & 3) * 8;    // V^T tile [128][32]: rows vc, vc+64

  // Q fragments (B-operand): qf[c][i] = Q[q0+q][c*16 + hi*8 + i], c=0..7
  bf16x8 qf[8];
#pragma unroll
  for (int c = 0; c < 8; ++c)
    qf[c] = *reinterpret_cast<const bf16x8*>(
        Qb + (long)(q0 + q) * 128 + c * 16 + hi * 8);

  f32x16 o[4];
#pragma unroll
  for (int dc = 0; dc < 4; ++dc)
#pragma unroll
    for (int r = 0; r < 16; ++r) o[dc][r] = 0.f;
  float mrun = -1e30f;
  float lrun = 0.f;   // per-lane partial (own 16 kv of each tile); combined at epilogue

  // prologue: issue tile 0's loads
  uint4v kreg0 = *reinterpret_cast<const uint4v*>(Kb + (long)kr * 128 + kc);
  uint4v kreg1 = *reinterpret_cast<const uint4v*>(Kb + (long)(kr + 16) * 128 + kc);
  uint4v vreg0 = *reinterpret_cast<const uint4v*>(Vb + (long)vc * 2048 + ko);
  uint4v vreg1 = *reinterpret_cast<const uint4v*>(Vb + (long)(vc + 64) * 2048 + ko);

  for (int kt = 0; kt < 64; ++kt) {
    __syncthreads();   // all waves done reading LDS from iteration kt-1
    *reinterpret_cast<uint4v*>(&Ks[kr][kc]) = kreg0;
    *reinterpret_cast<uint4v*>(&Ks[kr + 16][kc]) = kreg1;
    *reinterpret_cast<uint4v*>(&Vs[vc][ko]) = vreg0;
    *reinterpret_cast<uint4v*>(&Vs[vc + 64][ko]) = vreg1;
    __syncthreads();   // tile kt visible

    if (kt < 63) {     // T14: issue tile kt+1's loads now, consume next iter
      const int nv0 = (kt + 1) * 32;
      kreg0 = *reinterpret_cast<const uint4v*>(Kb + (long)(nv0 + kr) * 128 + kc);
      kreg1 = *reinterpret_cast<const uint4v*>(Kb + (long)(nv0 + kr + 16) * 128 + kc);
      vreg0 = *reinterpret_cast<const uint4v*>(Vb + (long)vc * 2048 + nv0 + ko);
      vreg1 = *reinterpret_cast<const uint4v*>(Vb + (long)(vc + 64) * 2048 + nv0 + ko);
    }

    // QK^T: S^T[kv][q], st reg r holds S^T[(r&3)+8*(r>>2)+4*hi][q]
    f32x16 st;
#pragma unroll
    for (int r = 0; r < 16; ++r) st[r] = 0.f;
#pragma unroll
    for (int c = 0; c < 8; ++c) {
      bf16x8 kf = *reinterpret_cast<const bf16x8*>(&Ks[q][c * 16 + hi * 8]);
      st = MFMA32(kf, qf[c], st);
    }

    // row max: 15 in-lane + 1 cross-hi
    float tm = st[0];
#pragma unroll
    for (int r = 1; r < 16; ++r) tm = fmaxf(tm, st[r]);
    tm = fmaxf(tm, __shfl_xor(tm, 32));

    // defer-max rescale
    float mcur = mrun;
    if (!__all(tm <= mcur + 8.0f)) {
      float mnew = fmaxf(mcur, tm);
      float al = __builtin_amdgcn_exp2f(mcur - mnew);
      mrun = mnew;
      mcur = mnew;
      lrun *= al;
#pragma unroll
      for (int r = 0; r < 16; ++r) {
        float ar = __shfl(al, (r & 3) + 8 * (r >> 2) + 4 * hi);
#pragma unroll
        for (int dc = 0; dc < 4; ++dc) o[dc][r] *= ar;
      }
    }

    float p[16];
    float rs = 0.f;
#pragma unroll
    for (int r = 0; r < 16; ++r) {
      p[r] = __builtin_amdgcn_exp2f(st[r] - mcur);
      rs += p[r];
    }
    lrun += rs;

    // pack pairs: pk[j] = kv pair per S^T row pattern
    unsigned pk[8];
#pragma unroll
    for (int j = 0; j < 8; ++j) pk[j] = pack2(p[2 * j], p[2 * j + 1]);

    // cross-hi exchange: each lane sends what its partner needs
    unsigned r1a = __shfl_xor(hi ? pk[0] : pk[2], 32);
    unsigned r1b = __shfl_xor(hi ? pk[1] : pk[3], 32);
    unsigned r2a = __shfl_xor(hi ? pk[4] : pk[6], 32);
    unsigned r2b = __shfl_xor(hi ? pk[5] : pk[7], 32);

    // assemble PV A-fragments: pa[kc2] = P[q][kc2*16 + hi*8 + 0..7]
    union { unsigned u[4]; bf16x8 v; } pa0, pa1;
    pa0.u[0] = hi ? r1a : pk[0];
    pa0.u[1] = hi ? r1b : pk[1];
    pa0.u[2] = hi ? pk[2] : r1a;
    pa0.u[3] = hi ? pk[3] : r1b;
    pa1.u[0] = hi ? r2a : pk[4];
    pa1.u[1] = hi ? r2b : pk[5];
    pa1.u[2] = hi ? pk[6] : r2a;
    pa1.u[3] = hi ? pk[7] : r2b;

    // PV: O[q][d] += P[q][kv] V[kv][d]; B-frag = V^T LDS read
#pragma unroll
    for (int dc = 0; dc < 4; ++dc) {
      bf16x8 vf0 = *reinterpret_cast<const bf16x8*>(&Vs[dc * 32 + q][hi * 8]);
      bf16x8 vf1 = *reinterpret_cast<const bf16x8*>(&Vs[dc * 32 + q][16 + hi * 8]);
      o[dc] = MFMA32(pa0.v, vf0, o[dc]);
      o[dc] = MFMA32(pa1.v, vf1, o[dc]);
    }
  }

  // epilogue: combine per-lane partial sums, normalize, store
  float ltot = lrun + __shfl_xor(lrun, 32);
  float inv = 1.f / ltot;     // valid for q = lane&31
#pragma unroll
  for (int r = 0; r < 16; ++r) {
    const int qr = (r & 3) + 8 * (r >> 2) + 4 * hi;
    float invr = __shfl(inv, qr);
    long row = (long)b * 2048 + q0 + qr;
#pragma unroll
    for (int dc = 0; dc < 4; ++dc)
      Fg[row * 128 + dc * 32 + q] = f2bf(o[dc][r] * invr);
  }
}

extern "C" void kernel_launch(void* const* d_in, const int* in_sizes, int n_in,
                              void* d_out, int out_size, void* d_ws, size_t ws_size,
                              hipStream_t stream)
{
  (void)in_sizes; (void)n_in; (void)out_size; (void)ws_size;
  const float* smiles = (const float*)d_in[0];
  const float* image  = (const float*)d_in[1];
  const float* Wv = (const float*)d_in[2]; const float* bv = (const float*)d_in[3];
  const float* Wk = (const float*)d_in[4]; const float* bk = (const float*)d_in[5];
  const float* Wq = (const float*)d_in[6]; const float* bq = (const float*)d_in[7];
  const float* Wd = (const float*)d_in[8]; const float* bd = (const float*)d_in[9];

  unsigned short* Qw = (unsigned short*)d_ws;          // [32][2048][128] bf16
  unsigned short* Kw = Qw + 8388608;                   // [32][2048][128] bf16
  unsigned short* Vw = Kw + 8388608;                   // [32][128][2048] bf16 (V^T)
  unsigned short* Fw = Vw + 8388608;                   // [32][2048][128] bf16 fusion

  // fold 1/sqrt(128) and log2(e) into Q so softmax uses exp2
  const float qscale = 1.4426950408889634f * 0.08838834764831845f;

  dim3 blk(256);
  proj_kernel<true, 0><<<dim3(1024), blk, 0, stream>>>(image,  Wq, bq, Qw, qscale);
  proj_kernel<true, 0><<<dim3(1024), blk, 0, stream>>>(smiles, Wk, bk, Kw, 1.f);
  proj_kernel<true, 1><<<dim3(1024), blk, 0, stream>>>(smiles, Wv, bv, Vw, 1.f);
  attn_kernel<<<dim3(16, 32), blk, 0, stream>>>(Qw, Kw, Vw, Fw);
  proj_kernel<false, 2><<<dim3(1024), blk, 0, stream>>>(Fw, Wd, bd, (float*)d_out, 1.f);
}